// Round 5
// baseline (16.611 us; speedup 1.0000x reference)
//
#include <hip/hip_runtime.h>

#define NN 128

typedef __attribute__((ext_vector_type(8))) short short8;
typedef __attribute__((ext_vector_type(4))) float f32x4;

__device__ __forceinline__ unsigned asu(float x) { return __float_as_uint(x); }
__device__ __forceinline__ float asf(unsigned u) { return __uint_as_float(u); }

// split 2 floats -> packed bf16-hi word + bf16-lo-residual word (truncation split;
// hi = top 16 bits, lo = bf16(x - hi); combined error ~2^-16 relative)
__device__ __forceinline__ void hilo2(float v0, float v1, unsigned& hw, unsigned& lw) {
    unsigned u0 = asu(v0), u1 = asu(v1);
    float r0 = v0 - asf(u0 & 0xffff0000u);
    float r1 = v1 - asf(u1 & 0xffff0000u);
    hw = (u0 >> 16) | (u1 & 0xffff0000u);
    lw = (asu(r0) >> 16) | (asu(r1) & 0xffff0000u);
}

// ---- Kernel 1: s1[t,i] = sum_k A[t,k,i]*W[k] + b0 ; s2[t,j] = sum_k A[t,k,j]*W[128+k]
// grid = 64 (one t per block; bid%8 -> same XCD as kernel2's t%8, warms L2)
__global__ __launch_bounds__(256) void s_compute(
    const float* __restrict__ A, const float* __restrict__ W,
    const float* __restrict__ b, float* __restrict__ s_ws)
{
    __shared__ float w_s[2 * NN];
    __shared__ float part1_s[4 * NN], part2_s[4 * NN];
    const int tid = threadIdx.x, lane = tid & 63, wid = tid >> 6;
    const int t = blockIdx.x;
    const float* At = A + (size_t)t * NN * NN;

    if (tid < 64)
        reinterpret_cast<float4*>(w_s)[tid] = reinterpret_cast<const float4*>(W)[tid];
    __syncthreads();

    const float4* A4 = reinterpret_cast<const float4*>(At);
    float p1[4] = {0,0,0,0}, p2[4] = {0,0,0,0};
    #pragma unroll
    for (int it = 0; it < 16; ++it) {
        int e4 = it * 256 + tid;          // fully coalesced
        int f  = e4 >> 5;                 // row (reduction index)
        float4 v = A4[e4];
        float w1 = w_s[f], w2 = w_s[NN + f];
        p1[0] += w1 * v.x; p1[1] += w1 * v.y; p1[2] += w1 * v.z; p1[3] += w1 * v.w;
        p2[0] += w2 * v.x; p2[1] += w2 * v.y; p2[2] += w2 * v.z; p2[3] += w2 * v.w;
    }
    #pragma unroll
    for (int q = 0; q < 4; ++q) {
        p1[q] += __shfl_xor(p1[q], 32);
        p2[q] += __shfl_xor(p2[q], 32);
    }
    if (lane < 32) {                      // cols lane*4+q
        float4 v1 = { p1[0], p1[1], p1[2], p1[3] };
        float4 v2 = { p2[0], p2[1], p2[2], p2[3] };
        *reinterpret_cast<float4*>(&part1_s[wid * NN + lane * 4]) = v1;
        *reinterpret_cast<float4*>(&part2_s[wid * NN + lane * 4]) = v2;
    }
    __syncthreads();
    if (tid < NN) {
        s_ws[t * NN + tid] = part1_s[tid] + part1_s[NN + tid]
                           + part1_s[2 * NN + tid] + part1_s[3 * NN + tid] + b[0];
    } else {
        int c = tid - NN;
        s_ws[64 * NN + t * NN + c] = part2_s[c] + part2_s[NN + c]
                                   + part2_s[2 * NN + c] + part2_s[3 * NN + c];
    }
}

// ---- Kernel 2: pure-dataflow PV. No LDS, no barriers.
// grid = 1024: t = bid&63, fb = (bid>>6)&7, ib = bid>>9. Wave tile: 16 i x 16 f.
__global__ __launch_bounds__(256, 4) void gat_pv(
    const float* __restrict__ A, const float* __restrict__ s_ws,
    float* __restrict__ out)
{
    const int tid  = threadIdx.x;
    const int lane = tid & 63, wid = tid >> 6;
    const int bid  = blockIdx.x;
    const int t    = bid & 63;
    const int f0   = ((bid >> 6) & 7) << 4;
    const int i0   = ((bid >> 9) << 6) + (wid << 4);
    const int r    = lane & 15;           // frag row (i) / B frag col (f)
    const int g    = lane >> 4;           // k sub-group 0..3

    // B fragments straight from global: B[j, f] = A[t, f, j]; lane holds
    // row f0+r of A at cols j = g*8 + 32k + e  (matches both MFMA operand k-order)
    const float* Brow = A + (size_t)t * NN * NN + (size_t)(f0 + r) * NN + g * 8;
    float4 bv[8];
    #pragma unroll
    for (int k = 0; k < 4; ++k) {
        bv[2 * k]     = *reinterpret_cast<const float4*>(Brow + 32 * k);
        bv[2 * k + 1] = *reinterpret_cast<const float4*>(Brow + 32 * k + 4);
    }
    // s2 for this lane's 32 j's; s1 for its row
    const float* s2p = s_ws + 64 * NN + t * NN + g * 8;
    float4 s2v[8];
    #pragma unroll
    for (int k = 0; k < 4; ++k) {
        s2v[2 * k]     = *reinterpret_cast<const float4*>(s2p + 32 * k);
        s2v[2 * k + 1] = *reinterpret_cast<const float4*>(s2p + 32 * k + 4);
    }
    float s1v = s_ws[t * NN + i0 + r];

    // softmax over row i0+r (lane group {r, r+16, r+32, r+48} -> shfl 16/32)
    float ev[32];
    float m = -3.4e38f;
    #pragma unroll
    for (int q = 0; q < 8; ++q) {
        float xs[4] = { s2v[q].x, s2v[q].y, s2v[q].z, s2v[q].w };
        #pragma unroll
        for (int e = 0; e < 4; ++e) {
            float x = s1v + xs[e];
            x = (x >= 0.f) ? x : 0.2f * x;    // leaky_relu 0.2
            ev[q * 4 + e] = x;
            m = fmaxf(m, x);
        }
    }
    m = fmaxf(m, __shfl_xor(m, 16));
    m = fmaxf(m, __shfl_xor(m, 32));
    float s = 0.f;
    #pragma unroll
    for (int c = 0; c < 32; ++c) { ev[c] = __expf(ev[c] - m); s += ev[c]; }
    s += __shfl_xor(s, 16);
    s += __shfl_xor(s, 32);
    const float inv = 1.0f / s;

    // pack alpha (scaled) and B to hi/lo bf16 fragments
    short8 ah[4], al[4], bh[4], bl[4];
    #pragma unroll
    for (int k = 0; k < 4; ++k) {
        union { short8 s8; unsigned u[4]; } H, L;
        #pragma unroll
        for (int p = 0; p < 4; ++p)
            hilo2(ev[8 * k + 2 * p] * inv, ev[8 * k + 2 * p + 1] * inv, H.u[p], L.u[p]);
        ah[k] = H.s8; al[k] = L.s8;
    }
    #pragma unroll
    for (int k = 0; k < 4; ++k) {
        union { short8 s8; unsigned u[4]; } H, L;
        hilo2(bv[2 * k].x,     bv[2 * k].y,     H.u[0], L.u[0]);
        hilo2(bv[2 * k].z,     bv[2 * k].w,     H.u[1], L.u[1]);
        hilo2(bv[2 * k + 1].x, bv[2 * k + 1].y, H.u[2], L.u[2]);
        hilo2(bv[2 * k + 1].z, bv[2 * k + 1].w, H.u[3], L.u[3]);
        bh[k] = H.s8; bl[k] = L.s8;
    }

    // PV: 3 hi/lo passes (ah*bh + ah*bl + al*bh); al*bl ~2^-16, dropped
    f32x4 acc = {0.f, 0.f, 0.f, 0.f};
    #pragma unroll
    for (int k = 0; k < 4; ++k)
        acc = __builtin_amdgcn_mfma_f32_16x16x32_bf16(ah[k], bh[k], acc, 0, 0, 0);
    #pragma unroll
    for (int k = 0; k < 4; ++k)
        acc = __builtin_amdgcn_mfma_f32_16x16x32_bf16(ah[k], bl[k], acc, 0, 0, 0);
    #pragma unroll
    for (int k = 0; k < 4; ++k)
        acc = __builtin_amdgcn_mfma_f32_16x16x32_bf16(al[k], bh[k], acc, 0, 0, 0);

    // C/D: col = lane&15 (f), row = g*4 + q (i)
    float* outt = out + (size_t)t * NN * NN + (size_t)(i0 + g * 4) * NN + f0 + r;
    #pragma unroll
    for (int q = 0; q < 4; ++q) outt[q * NN] = acc[q];
}

extern "C" void kernel_launch(void* const* d_in, const int* in_sizes, int n_in,
                              void* d_out, int out_size, void* d_ws, size_t ws_size,
                              hipStream_t stream) {
    const float* A = (const float*)d_in[0];
    const float* W = (const float*)d_in[1];
    const float* b = (const float*)d_in[2];
    float* out  = (float*)d_out;
    float* s_ws = (float*)d_ws;           // [0,8192): s1+b ; [8192,16384): s2
    s_compute<<<dim3(64),   dim3(256), 0, stream>>>(A, W, b, s_ws);
    gat_pv   <<<dim3(1024), dim3(256), 0, stream>>>(A, s_ws, out);
}

// Round 6
// 12.477 us; speedup vs baseline: 1.3314x; 1.3314x over previous
//
#include <hip/hip_runtime.h>

#define NN 128

typedef __attribute__((ext_vector_type(8))) short short8;
typedef __attribute__((ext_vector_type(4))) float f32x4;

// XOR-swizzled LDS index (units = shorts) for row-major [rows][128] bf16.
// Flips the 16B granule by row&7 -> column-slice ds_read_b128 across 16 rows
// hits all 32 banks at 2-way max (free). Bits <3 untouched -> 8/16B alignment kept.
__device__ __forceinline__ int SWZ(int r, int cs) {
    return (r << 7) + (cs ^ ((r & 7) << 3));
}

__device__ __forceinline__ unsigned asu(float x) { return __float_as_uint(x); }
__device__ __forceinline__ float asf(unsigned u) { return __uint_as_float(u); }

// Fused GAT attention, 512-thread blocks for 4 waves/SIMD.
// grid = 512: t = bid & 63 (i-blocks of one t land on one XCD), ib = bid >> 6 (16 rows).
// LDS ~73 KB -> 2 blocks/CU = 16 waves/CU.
__global__ __launch_bounds__(512, 4) void gat_fused(
    const float* __restrict__ A, const float* __restrict__ W,
    const float* __restrict__ b, float* __restrict__ out)
{
    __shared__ unsigned short Ah_s[NN * NN];   // bf16 hi of A[t,f,j]  (32 KB)
    __shared__ unsigned short Al_s[NN * NN];   // bf16 lo residual     (32 KB)
    __shared__ float part1_s[8 * NN];          // per-wave s1 partials (4 KB)
    __shared__ float part2_s[8 * NN];          // per-wave s2 partials (4 KB)
    __shared__ float s1_s[NN], s2_s[NN];       // 1 KB

    const int tid  = threadIdx.x;
    const int lane = tid & 63;
    const int wid  = tid >> 6;
    const int t    = blockIdx.x & 63;
    const int i0   = (blockIdx.x >> 6) << 4;
    const float* At = A + (size_t)t * NN * NN;

    // ---- stage A[t] -> (hi,lo) bf16 LDS (truncation split); fused fp32 s1/s2 partials ----
    {
        const float4* A4 = reinterpret_cast<const float4*>(At);
        float p1[4] = {0,0,0,0}, p2[4] = {0,0,0,0};
        #pragma unroll
        for (int it = 0; it < 8; ++it) {
            int e4 = it * 512 + tid;          // float4 index 0..4095, coalesced
            int f  = e4 >> 5;                 // A row (k of s1/s2)
            int cs = (e4 & 31) << 2;          // column (floats == shorts)
            float4 v = A4[e4];
            float w1 = W[f], w2 = W[NN + f];  // same-addr broadcast within 32 lanes
            p1[0] += w1 * v.x; p1[1] += w1 * v.y; p1[2] += w1 * v.z; p1[3] += w1 * v.w;
            p2[0] += w2 * v.x; p2[1] += w2 * v.y; p2[2] += w2 * v.z; p2[3] += w2 * v.w;
            unsigned ux = asu(v.x), uy = asu(v.y), uz = asu(v.z), uw = asu(v.w);
            float rx = v.x - asf(ux & 0xffff0000u);
            float ry = v.y - asf(uy & 0xffff0000u);
            float rz = v.z - asf(uz & 0xffff0000u);
            float rw = v.w - asf(uw & 0xffff0000u);
            uint2 hv, lv;
            hv.x = (ux >> 16) | (uy & 0xffff0000u);
            hv.y = (uz >> 16) | (uw & 0xffff0000u);
            lv.x = (asu(rx) >> 16) | (asu(ry) & 0xffff0000u);
            lv.y = (asu(rz) >> 16) | (asu(rw) & 0xffff0000u);
            int idx = SWZ(f, cs);
            *reinterpret_cast<uint2*>(&Ah_s[idx]) = hv;
            *reinterpret_cast<uint2*>(&Al_s[idx]) = lv;
        }
        // lane l and l^32 covered disjoint row sets of the same columns
        #pragma unroll
        for (int q = 0; q < 4; ++q) {
            p1[q] += __shfl_xor(p1[q], 32);
            p2[q] += __shfl_xor(p2[q], 32);
        }
        if (lane < 32) {                      // col = lane*4+q
            float4 v1 = { p1[0], p1[1], p1[2], p1[3] };
            float4 v2 = { p2[0], p2[1], p2[2], p2[3] };
            *reinterpret_cast<float4*>(&part1_s[wid * NN + lane * 4]) = v1;
            *reinterpret_cast<float4*>(&part2_s[wid * NN + lane * 4]) = v2;
        }
    }
    __syncthreads();

    if (tid < NN) {
        float s = b[0];
        #pragma unroll
        for (int w = 0; w < 8; ++w) s += part1_s[w * NN + tid];
        s1_s[tid] = s;
    } else if (tid < 2 * NN) {
        int c = tid - NN;
        float s = 0.f;
        #pragma unroll
        for (int w = 0; w < 8; ++w) s += part2_s[w * NN + c];
        s2_s[c] = s;
    }
    __syncthreads();

    // ---- per-wave 16i x 16f tile: B-frags -> regs, reg softmax -> A-frags, MFMA ----
    {
        const int f0 = wid << 4;              // wave's 16 output cols
        const int r  = lane & 15;             // frag row (i) / B row (f)
        const int g  = lane >> 4;             // k sub-group 0..3
        const int kg = g << 3;

        // B hi fragments (rows f0+r of Ah), read once
        short8 bh[4];
        #pragma unroll
        for (int k = 0; k < 4; ++k)
            bh[k] = *reinterpret_cast<const short8*>(&Ah_s[SWZ(f0 + r, k * 32 + kg)]);

        // softmax for row i0+r over this lane's 32 cols (32k + kg + e)
        // row group = lanes {r, r+16, r+32, r+48} -> shfl_xor 16/32
        float s1v = s1_s[i0 + r];
        float ev[32];
        float m = -3.4e38f;
        #pragma unroll
        for (int k = 0; k < 4; ++k) {
            float4 sa = *reinterpret_cast<const float4*>(&s2_s[k * 32 + kg]);
            float4 sb = *reinterpret_cast<const float4*>(&s2_s[k * 32 + kg + 4]);
            float xs[8] = { sa.x, sa.y, sa.z, sa.w, sb.x, sb.y, sb.z, sb.w };
            #pragma unroll
            for (int e = 0; e < 8; ++e) {
                float x = s1v + xs[e];
                x = (x >= 0.f) ? x : 0.2f * x;    // leaky_relu 0.2
                ev[k * 8 + e] = x;
                m = fmaxf(m, x);
            }
        }
        m = fmaxf(m, __shfl_xor(m, 16));
        m = fmaxf(m, __shfl_xor(m, 32));
        float s = 0.f;
        #pragma unroll
        for (int c = 0; c < 32; ++c) { ev[c] = __expf(ev[c] - m); s += ev[c]; }
        s += __shfl_xor(s, 16);
        s += __shfl_xor(s, 32);
        const float inv = 1.0f / s;

        // pack alpha -> hi/lo bf16 A-fragments
        short8 ah[4], al[4];
        #pragma unroll
        for (int k = 0; k < 4; ++k) {
            union { short8 s8; unsigned u[4]; } H, L;
            #pragma unroll
            for (int p = 0; p < 4; ++p) {
                float v0 = ev[k * 8 + 2 * p]     * inv;
                float v1 = ev[k * 8 + 2 * p + 1] * inv;
                unsigned u0 = asu(v0), u1 = asu(v1);
                float r0 = v0 - asf(u0 & 0xffff0000u);
                float r1 = v1 - asf(u1 & 0xffff0000u);
                H.u[p] = (u0 >> 16) | (u1 & 0xffff0000u);
                L.u[p] = (asu(r0) >> 16) | (asu(r1) & 0xffff0000u);
            }
            ah[k] = H.s8; al[k] = L.s8;
        }

        // pass 1+2 on bh (two independent acc chains), then load bl, pass 3
        f32x4 accA = {0.f,0.f,0.f,0.f}, accB = {0.f,0.f,0.f,0.f};
        #pragma unroll
        for (int k = 0; k < 4; ++k) {
            accA = __builtin_amdgcn_mfma_f32_16x16x32_bf16(ah[k], bh[k], accA, 0, 0, 0);
            accB = __builtin_amdgcn_mfma_f32_16x16x32_bf16(al[k], bh[k], accB, 0, 0, 0);
        }
        short8 bl[4];
        #pragma unroll
        for (int k = 0; k < 4; ++k)
            bl[k] = *reinterpret_cast<const short8*>(&Al_s[SWZ(f0 + r, k * 32 + kg)]);
        #pragma unroll
        for (int k = 0; k < 4; ++k)
            accB = __builtin_amdgcn_mfma_f32_16x16x32_bf16(ah[k], bl[k], accB, 0, 0, 0);

        // C/D: col = lane&15 (f), row = g*4 + q (i)
        float* outt = out + (size_t)t * NN * NN + (size_t)(i0 + g * 4) * NN + f0 + r;
        #pragma unroll
        for (int q = 0; q < 4; ++q) outt[q * NN] = accA[q] + accB[q];
    }
}

extern "C" void kernel_launch(void* const* d_in, const int* in_sizes, int n_in,
                              void* d_out, int out_size, void* d_ws, size_t ws_size,
                              hipStream_t stream) {
    const float* A = (const float*)d_in[0];
    const float* W = (const float*)d_in[1];
    const float* b = (const float*)d_in[2];
    float* out = (float*)d_out;
    gat_fused<<<dim3(512), dim3(512), 0, stream>>>(A, W, b, out);
}